// Round 5
// baseline (141.521 us; speedup 1.0000x reference)
//
#include <hip/hip_runtime.h>

#define B     128
#define NE    14951
#define NEP   14976     // 117*128, padded entity count
#define NR    1345
#define D     200
#define NL    116
#define D2    100
#define EBS   4         // batches per sub-group (per thread)
#define LOG2E 1.4426950408889634f

// ---- ws layout (floats), fast path ----
#define OFF_ET4  0                          // [50][NEP][4]  E transposed, d-chunked
#define OFF_LT4  (OFF_ET4 + 50*NEP*4)       // [29][NEP][4]  lit transposed
#define OFF_ST4  (OFF_LT4 + 29*NEP*4)       // [29][NEP][4]  q*L^2 transposed
#define OFF_WB   (OFF_ST4 + 29*NEP*4)       // [128][200]    complex weight w[b][d]
#define OFF_UB   (OFF_WB + 128*200)         // [128][116]    u = -2*q*a
#define OFF_FB   (OFF_UB + 128*116)         // [128][116]    w' = wnf*exp2(q*a^2)
#define WS_FLOATS (OFF_FB + 128*116)
#define WS_NEEDED ((size_t)WS_FLOATS * 4)

// ---------------- fused prep: 3 roles by blockIdx range ----------------
#define NB_A 3042
#define NB_B 1872
#define NB_C 64

__global__ __launch_bounds__(256) void prep_all(
    const int* __restrict__ e1_idx, const int* __restrict__ r_idx,
    const float* __restrict__ E, const float* __restrict__ R,
    const float* __restrict__ nf, const float* __restrict__ lit,
    const float* __restrict__ c, const float* __restrict__ var,
    float* __restrict__ ws)
{
    const int bid = blockIdx.x;
    const int t   = threadIdx.x;

    if (bid < NB_A) {                       // ---- transpose E ----
        const int ebk = bid % 234;
        const int cq  = (bid / 234) * 4 + (t >> 6);
        const int e   = ebk * 64 + (t & 63);
        if (cq >= 50) return;
        float4 v = make_float4(0.f, 0.f, 0.f, 0.f);
        if (e < NE) v = *(const float4*)(E + e*D + 4*cq);
        ((float4*)(ws + OFF_ET4))[cq*NEP + e] = v;
    } else if (bid < NB_A + NB_B) {         // ---- transpose lit + q*L^2 ----
        const int idx = bid - NB_A;
        const int ebk = idx % 234;
        const int cq  = (idx / 234) * 4 + (t >> 6);
        const int e   = ebk * 64 + (t & 63);
        if (cq >= 29) return;
        float4 L = make_float4(0.f, 0.f, 0.f, 0.f);
        if (e < NE) L = *(const float4*)(lit + e*NL + 4*cq);
        float4 vv = *(const float4*)(var + 4*cq);
        float4 s;
        s.x = (-LOG2E / vv.x) * L.x * L.x;
        s.y = (-LOG2E / vv.y) * L.y * L.y;
        s.z = (-LOG2E / vv.z) * L.z * L.z;
        s.w = (-LOG2E / vv.w) * L.w * L.w;
        ((float4*)(ws + OFF_LT4))[cq*NEP + e] = L;
        ((float4*)(ws + OFF_ST4))[cq*NEP + e] = s;
    } else {                                // ---- per-batch prep ----
        const int b  = (bid - NB_A - NB_B) * 2 + (t >> 7);
        const int tt = t & 127;
        const int e1 = e1_idx[b];
        const int r  = r_idx[b];
        float* wb = ws + OFF_WB;
        float* ub = ws + OFF_UB;
        float* fb = ws + OFF_FB;
        if (tt < D2) {
            float e1r = E[e1*D + tt],      e1i = E[e1*D + D2 + tt];
            float rr  = R[r*D + tt],       ri  = R[r*D + D2 + tt];
            wb[b*D + tt]      = e1r*rr - e1i*ri;
            wb[b*D + D2 + tt] = e1r*ri + e1i*rr;
        }
        if (tt < NL) {
            float a = lit[e1*NL + tt] - c[tt];
            float q = -LOG2E / var[tt];
            ub[b*NL + tt] = -2.0f * q * a;
            fb[b*NL + tt] = nf[r*NL + tt] * __builtin_amdgcn_exp2f(q * a * a);
        }
    }
}

// ---------------- main: 512 threads, 4 batch-subgroups share the e-slice ----------------
// grid = 936 = 117 eblk * 8 bblk ; each block: 128 entities x 16 batches.
// Sub-groups (tid>>7) issue identical per-lane load streams; __syncthreads()
// every few chunks bounds drift so subs 1-3 hit L1 instead of L2.

__global__ __launch_bounds__(512) void score_kernel(
    const float* __restrict__ et4, const float* __restrict__ lt4,
    const float* __restrict__ st4, const float* __restrict__ wb,
    const float* __restrict__ ub,  const float* __restrict__ fb,
    float* __restrict__ out)
{
    const int lid  = blockIdx.x;           // [0,936)
    const int p    = (lid & 7) * 117 + (lid >> 3);   // XCD-contiguous e-ranges
    const int eblk = p >> 3;               // [0,117)
    const int bb   = p & 7;                // [0,8)
    const int sub  = threadIdx.x >> 7;     // [0,4)
    const int b0   = bb * 16 + sub * EBS;
    const int e    = eblk * 128 + (threadIdx.x & 127);

    float acc[EBS];
#pragma unroll
    for (int j = 0; j < EBS; ++j) acc[j] = 0.f;

    const float4* E4 = (const float4*)et4;
    const float4* L4 = (const float4*)lt4;
    const float4* S4 = (const float4*)st4;

    // ---- score_l: acc[j] += sum_d w[b0+j][d] * E[e][d] ---- (4-deep prefetch)
    {
        float4 pf0 = E4[0*NEP + e];
        float4 pf1 = E4[1*NEP + e];
        float4 pf2 = E4[2*NEP + e];
        float4 pf3 = E4[3*NEP + e];
        for (int cq = 0; cq < 50; ++cq) {
            if ((cq & 7) == 0) __syncthreads();
            float4 ev = pf0;
            pf0 = pf1; pf1 = pf2; pf2 = pf3;
            pf3 = E4[min(cq + 4, 49)*NEP + e];
#pragma unroll
            for (int j = 0; j < EBS; ++j) {
                float4 wj = *(const float4*)(wb + (b0+j)*D + 4*cq);  // s_load
                acc[j] = fmaf(wj.x, ev.x, acc[j]);
                acc[j] = fmaf(wj.y, ev.y, acc[j]);
                acc[j] = fmaf(wj.z, ev.z, acc[j]);
                acc[j] = fmaf(wj.w, ev.w, acc[j]);
            }
        }
    }

    // ---- score_n: acc[j] += w'[j,l] * exp2( u[j,l]*L[e,l] + S[e,l] ) ---- (2-deep)
    {
        float4 lv0 = L4[0*NEP + e], sv0 = S4[0*NEP + e];
        float4 lv1 = L4[1*NEP + e], sv1 = S4[1*NEP + e];
        for (int cq = 0; cq < 29; ++cq) {
            if ((cq & 3) == 0) __syncthreads();
            float4 lv = lv0, sv = sv0;
            lv0 = lv1; sv0 = sv1;
            const int cqn = min(cq + 2, 28);
            lv1 = L4[cqn*NEP + e];
            sv1 = S4[cqn*NEP + e];
#pragma unroll
            for (int j = 0; j < EBS; ++j) {
                float4 uj = *(const float4*)(ub + (b0+j)*NL + 4*cq); // s_load
                float4 fj = *(const float4*)(fb + (b0+j)*NL + 4*cq); // s_load
                acc[j] = fmaf(fj.x, __builtin_amdgcn_exp2f(fmaf(uj.x, lv.x, sv.x)), acc[j]);
                acc[j] = fmaf(fj.y, __builtin_amdgcn_exp2f(fmaf(uj.y, lv.y, sv.y)), acc[j]);
                acc[j] = fmaf(fj.z, __builtin_amdgcn_exp2f(fmaf(uj.z, lv.z, sv.z)), acc[j]);
                acc[j] = fmaf(fj.w, __builtin_amdgcn_exp2f(fmaf(uj.w, lv.w, sv.w)), acc[j]);
            }
        }
    }

    // ---- sigmoid + coalesced store ----
    if (e < NE) {
#pragma unroll
        for (int j = 0; j < EBS; ++j) {
            float s = __builtin_amdgcn_rcpf(1.0f + __builtin_amdgcn_exp2f(acc[j] * -LOG2E));
            out[(b0+j)*NE + e] = s;
        }
    }
}

// ---------------- legacy fallback (ws < 26 MB) ----------------

#define ET  4
#define OFF_W   0
#define OFF_A   25600
#define OFF_WNF 40448
#define OFF_NQ  55296

__global__ __launch_bounds__(128) void prep_kernel_legacy(
    const int* __restrict__ e1_idx, const int* __restrict__ r_idx,
    const float* __restrict__ E, const float* __restrict__ R,
    const float* __restrict__ nf, const float* __restrict__ lit,
    const float* __restrict__ c, const float* __restrict__ var,
    float* __restrict__ ws)
{
    const int b = blockIdx.x;
    const int t = threadIdx.x;
    const int e1 = e1_idx[b];
    const int r  = r_idx[b];
    if (t < D2) {
        float e1r = E[e1*D + t], e1i = E[e1*D + D2 + t];
        float rr  = R[r*D + t],  ri  = R[r*D + D2 + t];
        ws[OFF_W + (t >> 2)*512        + (b << 2) + (t & 3)] = e1r*rr - e1i*ri;
        ws[OFF_W + ((t >> 2) + 25)*512 + (b << 2) + (t & 3)] = e1r*ri + e1i*rr;
    }
    if (t < NL) {
        ws[OFF_A   + (t >> 2)*512 + (b << 2) + (t & 3)] = lit[e1*NL + t] - c[t];
        ws[OFF_WNF + (t >> 2)*512 + (b << 2) + (t & 3)] = nf[r*NL + t];
        if (b == 0) ws[OFF_NQ + t] = -LOG2E / var[t];
    }
}

__global__ __launch_bounds__(128) void main_kernel_legacy(
    const float* __restrict__ E, const float* __restrict__ lit,
    const float* __restrict__ ws, float* __restrict__ out)
{
    const int b  = threadIdx.x;
    const int e0 = blockIdx.x * ET;
    const float4* w4   = (const float4*)(ws + OFF_W);
    const float4* a4   = (const float4*)(ws + OFF_A);
    const float4* wnf4 = (const float4*)(ws + OFF_WNF);
    const float*  nq   = ws + OFF_NQ;
    int eidx[ET];
#pragma unroll
    for (int j = 0; j < ET; ++j) eidx[j] = min(e0 + j, NE - 1);
    float acc[ET];
#pragma unroll
    for (int j = 0; j < ET; ++j) acc[j] = 0.0f;
    for (int dc = 0; dc < D; dc += 4) {
        float4 wv = w4[(dc >> 2)*B + b];
#pragma unroll
        for (int j = 0; j < ET; ++j) {
            float4 ev = *(const float4*)(E + eidx[j]*D + dc);
            acc[j] = fmaf(wv.x, ev.x, acc[j]);
            acc[j] = fmaf(wv.y, ev.y, acc[j]);
            acc[j] = fmaf(wv.z, ev.z, acc[j]);
            acc[j] = fmaf(wv.w, ev.w, acc[j]);
        }
    }
    for (int lc = 0; lc < NL; lc += 4) {
        float4 av = a4[(lc >> 2)*B + b];
        float4 wv = wnf4[(lc >> 2)*B + b];
        float4 q  = *(const float4*)(nq + lc);
#pragma unroll
        for (int j = 0; j < ET; ++j) {
            float4 lv = *(const float4*)(lit + eidx[j]*NL + lc);
            float t0 = av.x - lv.x, t1 = av.y - lv.y, t2 = av.z - lv.z, t3 = av.w - lv.w;
            acc[j] += wv.x * __builtin_amdgcn_exp2f(t0*t0*q.x);
            acc[j] += wv.y * __builtin_amdgcn_exp2f(t1*t1*q.y);
            acc[j] += wv.z * __builtin_amdgcn_exp2f(t2*t2*q.z);
            acc[j] += wv.w * __builtin_amdgcn_exp2f(t3*t3*q.w);
        }
    }
#pragma unroll
    for (int j = 0; j < ET; ++j) {
        float s = 1.0f / (1.0f + __builtin_amdgcn_exp2f(acc[j] * -LOG2E));
        int e = e0 + j;
        if (e < NE) out[b*NE + e] = s;
    }
}

// ---------------- launch ----------------

extern "C" void kernel_launch(void* const* d_in, const int* in_sizes, int n_in,
                              void* d_out, int out_size, void* d_ws, size_t ws_size,
                              hipStream_t stream) {
    const int*   e1_idx = (const int*)d_in[0];
    const int*   r_idx  = (const int*)d_in[1];
    const float* E      = (const float*)d_in[2];
    const float* R      = (const float*)d_in[3];
    const float* nf     = (const float*)d_in[4];
    const float* lit    = (const float*)d_in[5];
    const float* c      = (const float*)d_in[6];
    const float* var    = (const float*)d_in[7];
    float* out = (float*)d_out;
    float* ws  = (float*)d_ws;

    if (ws_size >= WS_NEEDED) {
        prep_all<<<NB_A + NB_B + NB_C, 256, 0, stream>>>(
            e1_idx, r_idx, E, R, nf, lit, c, var, ws);
        score_kernel<<<117 * 8, 512, 0, stream>>>(
            ws + OFF_ET4, ws + OFF_LT4, ws + OFF_ST4,
            ws + OFF_WB, ws + OFF_UB, ws + OFF_FB, out);
    } else {
        prep_kernel_legacy<<<B, 128, 0, stream>>>(e1_idx, r_idx, E, R, nf, lit, c, var, ws);
        main_kernel_legacy<<<(NE + ET - 1)/ET, B, 0, stream>>>(E, lit, ws, out);
    }
}

// Round 6
// 62.303 us; speedup vs baseline: 2.2715x; 2.2715x over previous
//
#include <hip/hip_runtime.h>

#define B     128
#define NE    14951
#define NEP   14976     // 117*128, padded entity count
#define NR    1345
#define D     200
#define NL    116
#define D2    100
#define EB    4         // batches per block in main kernel
#define LOG2E 1.4426950408889634f

// ---- ws layout (floats), fast path ----
#define OFF_ET4  0                          // [50][NEP][4]  E transposed, d-chunked
#define OFF_LT4  (OFF_ET4 + 50*NEP*4)       // [29][NEP][4]  lit transposed
#define OFF_ST4  (OFF_LT4 + 29*NEP*4)       // [29][NEP][4]  q*L^2 transposed
#define OFF_WB   (OFF_ST4 + 29*NEP*4)       // [128][200]    complex weight w[b][d]
#define OFF_UB   (OFF_WB + 128*200)         // [128][116]    u = -2*q*a
#define OFF_FB   (OFF_UB + 128*116)         // [128][116]    w' = wnf*exp2(q*a^2)
#define WS_FLOATS (OFF_FB + 128*116)
#define WS_NEEDED ((size_t)WS_FLOATS * 4)

// ---------------- fused prep: 3 roles by blockIdx range ----------------
#define NB_A 3042
#define NB_B 1872
#define NB_C 64

__global__ __launch_bounds__(256) void prep_all(
    const int* __restrict__ e1_idx, const int* __restrict__ r_idx,
    const float* __restrict__ E, const float* __restrict__ R,
    const float* __restrict__ nf, const float* __restrict__ lit,
    const float* __restrict__ c, const float* __restrict__ var,
    float* __restrict__ ws)
{
    const int bid = blockIdx.x;
    const int t   = threadIdx.x;

    if (bid < NB_A) {                       // ---- transpose E ----
        const int ebk = bid % 234;
        const int cq  = (bid / 234) * 4 + (t >> 6);
        const int e   = ebk * 64 + (t & 63);
        if (cq >= 50) return;
        float4 v = make_float4(0.f, 0.f, 0.f, 0.f);
        if (e < NE) v = *(const float4*)(E + e*D + 4*cq);
        ((float4*)(ws + OFF_ET4))[cq*NEP + e] = v;
    } else if (bid < NB_A + NB_B) {         // ---- transpose lit + q*L^2 ----
        const int idx = bid - NB_A;
        const int ebk = idx % 234;
        const int cq  = (idx / 234) * 4 + (t >> 6);
        const int e   = ebk * 64 + (t & 63);
        if (cq >= 29) return;
        float4 L = make_float4(0.f, 0.f, 0.f, 0.f);
        if (e < NE) L = *(const float4*)(lit + e*NL + 4*cq);
        float4 vv = *(const float4*)(var + 4*cq);
        float4 s;
        s.x = (-LOG2E / vv.x) * L.x * L.x;
        s.y = (-LOG2E / vv.y) * L.y * L.y;
        s.z = (-LOG2E / vv.z) * L.z * L.z;
        s.w = (-LOG2E / vv.w) * L.w * L.w;
        ((float4*)(ws + OFF_LT4))[cq*NEP + e] = L;
        ((float4*)(ws + OFF_ST4))[cq*NEP + e] = s;
    } else {                                // ---- per-batch prep ----
        const int b  = (bid - NB_A - NB_B) * 2 + (t >> 7);
        const int tt = t & 127;
        const int e1 = e1_idx[b];
        const int r  = r_idx[b];
        float* wb = ws + OFF_WB;
        float* ub = ws + OFF_UB;
        float* fb = ws + OFF_FB;
        if (tt < D2) {
            float e1r = E[e1*D + tt],      e1i = E[e1*D + D2 + tt];
            float rr  = R[r*D + tt],       ri  = R[r*D + D2 + tt];
            wb[b*D + tt]      = e1r*rr - e1i*ri;
            wb[b*D + D2 + tt] = e1r*ri + e1i*rr;
        }
        if (tt < NL) {
            float a = lit[e1*NL + tt] - c[tt];
            float q = -LOG2E / var[tt];
            ub[b*NL + tt] = -2.0f * q * a;
            fb[b*NL + tt] = nf[r*NL + tt] * __builtin_amdgcn_exp2f(q * a * a);
        }
    }
}

// ---------------- main: lane = entity, 4-deep barrier-free pipeline ----------------

#define SL_STEP(pf, cq) do {                                              \
    _Pragma("unroll")                                                     \
    for (int j = 0; j < EB; ++j) {                                        \
        float4 wj = *(const float4*)(wb + (b0+j)*D + 4*(cq));             \
        acc[j] = fmaf(wj.x, (pf).x, acc[j]);                              \
        acc[j] = fmaf(wj.y, (pf).y, acc[j]);                              \
        acc[j] = fmaf(wj.z, (pf).z, acc[j]);                              \
        acc[j] = fmaf(wj.w, (pf).w, acc[j]);                              \
    }                                                                     \
} while (0)

#define SN_STEP(lv, sv, cq) do {                                          \
    _Pragma("unroll")                                                     \
    for (int j = 0; j < EB; ++j) {                                        \
        float4 uj = *(const float4*)(ub + (b0+j)*NL + 4*(cq));            \
        float4 fj = *(const float4*)(fb + (b0+j)*NL + 4*(cq));            \
        acc[j] = fmaf(fj.x, __builtin_amdgcn_exp2f(fmaf(uj.x,(lv).x,(sv).x)), acc[j]); \
        acc[j] = fmaf(fj.y, __builtin_amdgcn_exp2f(fmaf(uj.y,(lv).y,(sv).y)), acc[j]); \
        acc[j] = fmaf(fj.z, __builtin_amdgcn_exp2f(fmaf(uj.z,(lv).z,(sv).z)), acc[j]); \
        acc[j] = fmaf(fj.w, __builtin_amdgcn_exp2f(fmaf(uj.w,(lv).w,(sv).w)), acc[j]); \
    }                                                                     \
} while (0)

__global__ __launch_bounds__(128) void score_kernel(
    const float* __restrict__ et4, const float* __restrict__ lt4,
    const float* __restrict__ st4, const float* __restrict__ wb,
    const float* __restrict__ ub,  const float* __restrict__ fb,
    float* __restrict__ out)
{
    // grid = 3744 = 117 eblk * 32 bblk; partition e-range per XCD (lid&7)
    const int lid  = blockIdx.x;
    const int p    = (lid & 7) * 468 + (lid >> 3);
    const int eblk = p >> 5;            // 0..116
    const int bblk = p & 31;            // 0..31
    const int e    = eblk * 128 + threadIdx.x;
    const int b0   = bblk * EB;

    float acc[EB];
#pragma unroll
    for (int j = 0; j < EB; ++j) acc[j] = 0.f;

    const float4* E4 = (const float4*)et4;
    const float4* L4 = (const float4*)lt4;
    const float4* S4 = (const float4*)st4;

    // ---- score_l: 50 chunks, 4-deep rolling prefetch, named slots ----
    {
        float4 pf0 = E4[0*NEP + e];
        float4 pf1 = E4[1*NEP + e];
        float4 pf2 = E4[2*NEP + e];
        float4 pf3 = E4[3*NEP + e];
        for (int cq0 = 0; cq0 < 48; cq0 += 4) {
            SL_STEP(pf0, cq0 + 0); pf0 = E4[min(cq0 + 4, 49)*NEP + e];
            SL_STEP(pf1, cq0 + 1); pf1 = E4[min(cq0 + 5, 49)*NEP + e];
            SL_STEP(pf2, cq0 + 2); pf2 = E4[min(cq0 + 6, 49)*NEP + e];
            SL_STEP(pf3, cq0 + 3); pf3 = E4[min(cq0 + 7, 49)*NEP + e];
        }
        // after loop: pf0 = chunk 48 (loaded at cq0=44), pf1 = chunk 49
        SL_STEP(pf0, 48);
        SL_STEP(pf1, 49);
    }

    // ---- score_n: 29 chunks, 4-deep rolling prefetch ----
    {
        float4 lv0 = L4[0*NEP + e], sv0 = S4[0*NEP + e];
        float4 lv1 = L4[1*NEP + e], sv1 = S4[1*NEP + e];
        float4 lv2 = L4[2*NEP + e], sv2 = S4[2*NEP + e];
        float4 lv3 = L4[3*NEP + e], sv3 = S4[3*NEP + e];
        for (int cq0 = 0; cq0 < 28; cq0 += 4) {
            SN_STEP(lv0, sv0, cq0 + 0);
            lv0 = L4[min(cq0 + 4, 28)*NEP + e]; sv0 = S4[min(cq0 + 4, 28)*NEP + e];
            SN_STEP(lv1, sv1, cq0 + 1);
            lv1 = L4[min(cq0 + 5, 28)*NEP + e]; sv1 = S4[min(cq0 + 5, 28)*NEP + e];
            SN_STEP(lv2, sv2, cq0 + 2);
            lv2 = L4[min(cq0 + 6, 28)*NEP + e]; sv2 = S4[min(cq0 + 6, 28)*NEP + e];
            SN_STEP(lv3, sv3, cq0 + 3);
            lv3 = L4[min(cq0 + 7, 28)*NEP + e]; sv3 = S4[min(cq0 + 7, 28)*NEP + e];
        }
        // after loop: lv0/sv0 = chunk 28 (loaded at cq0=24)
        SN_STEP(lv0, sv0, 28);
    }

    // ---- sigmoid + coalesced store ----
    if (e < NE) {
#pragma unroll
        for (int j = 0; j < EB; ++j) {
            float s = __builtin_amdgcn_rcpf(1.0f + __builtin_amdgcn_exp2f(acc[j] * -LOG2E));
            out[(b0+j)*NE + e] = s;
        }
    }
}

// ---------------- legacy fallback (ws < 26 MB) ----------------

#define ET  4
#define OFF_W   0
#define OFF_A   25600
#define OFF_WNF 40448
#define OFF_NQ  55296

__global__ __launch_bounds__(128) void prep_kernel_legacy(
    const int* __restrict__ e1_idx, const int* __restrict__ r_idx,
    const float* __restrict__ E, const float* __restrict__ R,
    const float* __restrict__ nf, const float* __restrict__ lit,
    const float* __restrict__ c, const float* __restrict__ var,
    float* __restrict__ ws)
{
    const int b = blockIdx.x;
    const int t = threadIdx.x;
    const int e1 = e1_idx[b];
    const int r  = r_idx[b];
    if (t < D2) {
        float e1r = E[e1*D + t], e1i = E[e1*D + D2 + t];
        float rr  = R[r*D + t],  ri  = R[r*D + D2 + t];
        ws[OFF_W + (t >> 2)*512        + (b << 2) + (t & 3)] = e1r*rr - e1i*ri;
        ws[OFF_W + ((t >> 2) + 25)*512 + (b << 2) + (t & 3)] = e1r*ri + e1i*rr;
    }
    if (t < NL) {
        ws[OFF_A   + (t >> 2)*512 + (b << 2) + (t & 3)] = lit[e1*NL + t] - c[t];
        ws[OFF_WNF + (t >> 2)*512 + (b << 2) + (t & 3)] = nf[r*NL + t];
        if (b == 0) ws[OFF_NQ + t] = -LOG2E / var[t];
    }
}

__global__ __launch_bounds__(128) void main_kernel_legacy(
    const float* __restrict__ E, const float* __restrict__ lit,
    const float* __restrict__ ws, float* __restrict__ out)
{
    const int b  = threadIdx.x;
    const int e0 = blockIdx.x * ET;
    const float4* w4   = (const float4*)(ws + OFF_W);
    const float4* a4   = (const float4*)(ws + OFF_A);
    const float4* wnf4 = (const float4*)(ws + OFF_WNF);
    const float*  nq   = ws + OFF_NQ;
    int eidx[ET];
#pragma unroll
    for (int j = 0; j < ET; ++j) eidx[j] = min(e0 + j, NE - 1);
    float acc[ET];
#pragma unroll
    for (int j = 0; j < ET; ++j) acc[j] = 0.0f;
    for (int dc = 0; dc < D; dc += 4) {
        float4 wv = w4[(dc >> 2)*B + b];
#pragma unroll
        for (int j = 0; j < ET; ++j) {
            float4 ev = *(const float4*)(E + eidx[j]*D + dc);
            acc[j] = fmaf(wv.x, ev.x, acc[j]);
            acc[j] = fmaf(wv.y, ev.y, acc[j]);
            acc[j] = fmaf(wv.z, ev.z, acc[j]);
            acc[j] = fmaf(wv.w, ev.w, acc[j]);
        }
    }
    for (int lc = 0; lc < NL; lc += 4) {
        float4 av = a4[(lc >> 2)*B + b];
        float4 wv = wnf4[(lc >> 2)*B + b];
        float4 q  = *(const float4*)(nq + lc);
#pragma unroll
        for (int j = 0; j < ET; ++j) {
            float4 lv = *(const float4*)(lit + eidx[j]*NL + lc);
            float t0 = av.x - lv.x, t1 = av.y - lv.y, t2 = av.z - lv.z, t3 = av.w - lv.w;
            acc[j] += wv.x * __builtin_amdgcn_exp2f(t0*t0*q.x);
            acc[j] += wv.y * __builtin_amdgcn_exp2f(t1*t1*q.y);
            acc[j] += wv.z * __builtin_amdgcn_exp2f(t2*t2*q.z);
            acc[j] += wv.w * __builtin_amdgcn_exp2f(t3*t3*q.w);
        }
    }
#pragma unroll
    for (int j = 0; j < ET; ++j) {
        float s = 1.0f / (1.0f + __builtin_amdgcn_exp2f(acc[j] * -LOG2E));
        int e = e0 + j;
        if (e < NE) out[b*NE + e] = s;
    }
}

// ---------------- launch ----------------

extern "C" void kernel_launch(void* const* d_in, const int* in_sizes, int n_in,
                              void* d_out, int out_size, void* d_ws, size_t ws_size,
                              hipStream_t stream) {
    const int*   e1_idx = (const int*)d_in[0];
    const int*   r_idx  = (const int*)d_in[1];
    const float* E      = (const float*)d_in[2];
    const float* R      = (const float*)d_in[3];
    const float* nf     = (const float*)d_in[4];
    const float* lit    = (const float*)d_in[5];
    const float* c      = (const float*)d_in[6];
    const float* var    = (const float*)d_in[7];
    float* out = (float*)d_out;
    float* ws  = (float*)d_ws;

    if (ws_size >= WS_NEEDED) {
        prep_all<<<NB_A + NB_B + NB_C, 256, 0, stream>>>(
            e1_idx, r_idx, E, R, nf, lit, c, var, ws);
        score_kernel<<<117 * 32, 128, 0, stream>>>(
            ws + OFF_ET4, ws + OFF_LT4, ws + OFF_ST4,
            ws + OFF_WB, ws + OFF_UB, ws + OFF_FB, out);
    } else {
        prep_kernel_legacy<<<B, 128, 0, stream>>>(e1_idx, r_idx, E, R, nf, lit, c, var, ws);
        main_kernel_legacy<<<(NE + ET - 1)/ET, B, 0, stream>>>(E, lit, ws, out);
    }
}